// Round 7
// baseline (1473.359 us; speedup 1.0000x reference)
//
#include <hip/hip_runtime.h>

#define BB 2
#define NN 4096
#define NP 1024
#define MM 32
#define CC 35
#define CIN 32

typedef float f2 __attribute__((ext_vector_type(2)));

// ---------------- FPS: one block per batch, 4 waves ----------------
// Serial-chain-minimized design (R6 showed time invariant to update
// throughput => latency chain dominates):
//  * winner COORDS ride the reduction as payload -> no pc[far] LDS read
//  * in-wave reduce = 4 DPP rounds only (row of 16 converges); the 16
//    row-winners go to LDS; post-barrier every lane reads slot (t&15)
//    and 4 more DPP rounds converge the block. NO 64-lane LDS shuffles
//    anywhere on the chain.
// (dist,idx) packed in u64: dist>=0 => float bits monotonic; low word =
// ~idx so u64 max picks smallest index on ties (matches jnp.argmax).
// DPP note: 0x141/0x140 are half-row/row mirrors (xor7/xor15 in-row) --
// valid as xor4/xor8 *combiners* because sub-groups are converged by the
// time they run (partner lane holds its group's winner).
#define RED_DPP(CTRL) do { \
    int _klo = (int)(unsigned)key, _khi = (int)(unsigned)(key >> 32); \
    int _oklo = __builtin_amdgcn_mov_dpp(_klo, CTRL, 0xF, 0xF, true); \
    int _okhi = __builtin_amdgcn_mov_dpp(_khi, CTRL, 0xF, 0xF, true); \
    int _owx = __builtin_amdgcn_mov_dpp(__float_as_int(wx), CTRL, 0xF, 0xF, true); \
    int _owy = __builtin_amdgcn_mov_dpp(__float_as_int(wy), CTRL, 0xF, 0xF, true); \
    int _owz = __builtin_amdgcn_mov_dpp(__float_as_int(wz), CTRL, 0xF, 0xF, true); \
    unsigned long long _ok = ((unsigned long long)(unsigned)_okhi << 32) | (unsigned)_oklo; \
    if (_ok > key) { key = _ok; wx = __int_as_float(_owx); wy = __int_as_float(_owy); wz = __int_as_float(_owz); } \
} while (0)

__launch_bounds__(256)
__global__ void fps_kernel(const float* __restrict__ xyz, float* __restrict__ newxyz_out)
{
#pragma clang fp contract(off)
    const int b = blockIdx.x;
    const int t = threadIdx.x;
    const float* xb = xyz + b * NN * 3;

    __shared__ float nxs[NP * 3];            // newxyz staging
    __shared__ unsigned red[2][16][8];       // double-buffered row-winner slots

    f2 px[8], py[8], pz[8], dist[8];
#pragma unroll
    for (int k = 0; k < 16; ++k) {
        int n = t + 256 * k;
        px[k >> 1][k & 1] = xb[n * 3 + 0];
        py[k >> 1][k & 1] = xb[n * 3 + 1];
        pz[k >> 1][k & 1] = xb[n * 3 + 2];
        dist[k >> 1][k & 1] = 1e10f;
    }
    __syncthreads();

    // current selected point = point 0
    float wx = xb[0], wy = xb[1], wz = xb[2];

    for (int s = 0; s < NP; ++s) {
        if (t == 0) {
            nxs[s * 3 + 0] = wx;
            nxs[s * 3 + 1] = wy;
            nxs[s * 3 + 2] = wz;
        }
        const f2 cx = { wx, wx }, cy = { wy, wy }, cz = { wz, wz };

        // update dists (packed), local argmax in ascending point order
        float bv = -1.0f; int bi = 0;
#pragma unroll
        for (int j = 0; j < 8; ++j) {
            f2 dx = px[j] - cx, dy = py[j] - cy, dz = pz[j] - cz;
            f2 d = (dx * dx + dy * dy) + dz * dz;
            f2 dd = __builtin_elementwise_min(dist[j], d);
            dist[j] = dd;
            if (dd.x > bv) { bv = dd.x; bi = t + 256 * (2 * j); }
            if (dd.y > bv) { bv = dd.y; bi = t + 256 * (2 * j + 1); }
        }

        // candidate = own best point; coords as payload
        unsigned long long key =
            ((unsigned long long)(unsigned)__float_as_int(bv) << 32)
            | (unsigned)(0xFFFFFFFFu - (unsigned)bi);
        wx = px[(bi >> 8) >> 1][(bi >> 8) & 1];
        wy = py[(bi >> 8) >> 1][(bi >> 8) & 1];
        wz = pz[(bi >> 8) >> 1][(bi >> 8) & 1];

        RED_DPP(0xB1);   // xor 1
        RED_DPP(0x4E);   // xor 2
        RED_DPP(0x141);  // cross-quad combine (quads converged)
        RED_DPP(0x140);  // cross-octet combine (octets converged) -> row of 16 converged

        const int buf = s & 1;
        if ((t & 15) == 0) {
            unsigned* sp = red[buf][t >> 4];
            sp[0] = (unsigned)key;
            sp[1] = (unsigned)(key >> 32);
            sp[2] = __float_as_uint(wx);
            sp[3] = __float_as_uint(wy);
            sp[4] = __float_as_uint(wz);
        }
        __syncthreads();

        {   // every lane grabs one of the 16 row-winners; 4 DPP rounds converge
            const unsigned* sp = red[buf][t & 15];
            unsigned klo = sp[0], khi = sp[1];
            key = ((unsigned long long)khi << 32) | klo;
            wx = __uint_as_float(sp[2]);
            wy = __uint_as_float(sp[3]);
            wz = __uint_as_float(sp[4]);
        }
        RED_DPP(0xB1);
        RED_DPP(0x4E);
        RED_DPP(0x141);
        RED_DPP(0x140);
        // (wx,wy,wz) = coords of global argmax; uniform across block
    }

    __syncthreads();
    // coalesced dump of staged newxyz: (B, NP, 3) flat
#pragma unroll
    for (int j = 0; j < 12; ++j) {
        int i = t + 256 * j;
        newxyz_out[b * NP * 3 + i] = nxs[i];
    }
}

// ---------------- kNN: one block per (b,p) ----------------
__launch_bounds__(256)
__global__ void knn_kernel(const float* __restrict__ xyz, const float* __restrict__ newxyz,
                           int* __restrict__ knn_out)
{
#pragma clang fp contract(off)
    const int bp = blockIdx.x;
    const int b = bp >> 10;
    const int t = threadIdx.x;
    const float* xb = xyz + b * NN * 3;

    const float qx = newxyz[bp * 3 + 0];
    const float qy = newxyz[bp * 3 + 1];
    const float qz = newxyz[bp * 3 + 2];
    const float qn = (qx * qx + qy * qy) + qz * qz;

    __shared__ float dist[NN];
    __shared__ float redV[4];
    __shared__ int   redI[4];

#pragma unroll
    for (int k = 0; k < 16; ++k) {
        int n = t + 256 * k;
        float x = xb[n * 3 + 0], y = xb[n * 3 + 1], z = xb[n * 3 + 2];
        float xn = (x * x + y * y) + z * z;
        float dt = (qx * x + qy * y) + qz * z;
        dist[n] = (qn + xn) - 2.0f * dt;
    }
    __syncthreads();

    for (int r = 0; r < MM; ++r) {
        float bv = 1e30f; int bi = NN;
#pragma unroll
        for (int k = 0; k < 16; ++k) {
            int n = t + 256 * k;
            float v = dist[n];
            if (v < bv) { bv = v; bi = n; }
        }
#pragma unroll
        for (int off = 1; off < 64; off <<= 1) {
            float ov = __shfl_xor(bv, off);
            int   oi = __shfl_xor(bi, off);
            if (ov < bv || (ov == bv && oi < bi)) { bv = ov; bi = oi; }
        }
        if ((t & 63) == 0) { redV[t >> 6] = bv; redI[t >> 6] = bi; }
        __syncthreads();
        bv = redV[0]; bi = redI[0];
#pragma unroll
        for (int w = 1; w < 4; ++w) {
            float ov = redV[w]; int oi = redI[w];
            if (ov < bv || (ov == bv && oi < bi)) { bv = ov; bi = oi; }
        }
        if (t == 0) { knn_out[bp * MM + r] = bi; dist[bi] = 1e30f; }
        __syncthreads();
    }
}

// ---------------- prep: transpose MLP weights ----------------
__global__ void prep_kernel(const float* __restrict__ w1, const float* __restrict__ w2,
                            const float* __restrict__ w3,
                            float* __restrict__ w1T, float* __restrict__ w2T,
                            float* __restrict__ w3T)
{
    int t = blockIdx.x * 256 + threadIdx.x;
    int stride = gridDim.x * 256;
    for (int i = t; i < 64 * CC; i += stride) { int o = i / CC, c = i % CC; w1T[c * 64 + o] = w1[i]; }
    for (int i = t; i < 64 * 64; i += stride) { int o = i >> 6, c = i & 63; w2T[c * 64 + o] = w2[i]; }
    for (int i = t; i < 128 * 64; i += stride) { int o = i >> 6, c = i & 63; w3T[c * 128 + o] = w3[i]; }
}

// ---------------- fused gather + AFA + MLP + maxpool ----------------
__launch_bounds__(256)
__global__ void afa_mlp_kernel(const float* __restrict__ xyz, const float* __restrict__ feat,
                               const float* __restrict__ newxyz, const int* __restrict__ knn,
                               const float* __restrict__ aw1, const float* __restrict__ ab1,
                               const float* __restrict__ aw2, const float* __restrict__ ab2,
                               const float* __restrict__ aww, const float* __restrict__ abw,
                               const float* __restrict__ w1T, const float* __restrict__ b1,
                               const float* __restrict__ w2T, const float* __restrict__ b2,
                               const float* __restrict__ w3T, const float* __restrict__ b3,
                               float* __restrict__ out)
{
    const int bp = blockIdx.x;
    const int b = bp >> 10, p = bp & 1023;
    const int t = threadIdx.x;

    __shared__ float xs[CC][MM];
    __shared__ float nfs[CC][MM];
    __shared__ int   idxs[MM];
    __shared__ float h1s[64][33];
    __shared__ float h2s[64][33];
    __shared__ float pmax[128][2];

    if (t < MM) idxs[t] = knn[bp * MM + t];
    __syncthreads();

    {   // gather x = concat(gxyz, gfeat) as [C][M]
        const int m = t & 31, c0 = t >> 5;
        const int id = idxs[m];
        for (int c = c0; c < CC; c += 8) {
            float v;
            if (c < 3) v = xyz[(b * NN + id) * 3 + c] - newxyz[bp * 3 + c];
            else       v = feat[(b * CIN + (c - 3)) * NN + id];
            xs[c][m] = v;
        }
    }
    __syncthreads();

    // ---- AFA: thread (i = t>>3, jg = t&7) handles j in {jg, jg+8, jg+16, jg+24}
    const int i = t >> 3, jg = t & 7;
    float xi[CC], afa[CC];
#pragma unroll
    for (int c = 0; c < CC; ++c) { xi[c] = xs[c][i]; afa[c] = 0.0f; }

#pragma unroll
    for (int jk = 0; jk < 4; ++jk) {
        const int j = jg + 8 * jk;
        float pcol[CC];
#pragma unroll
        for (int c = 0; c < CC; ++c) {
            float v = xi[c] - xs[c][j];
            if (i == j) v = xi[c];       // xi - xj + xi*eye
            pcol[c] = v;
        }
        float h1[16];
#pragma unroll
        for (int o = 0; o < 16; ++o) {
            float acc = ab1[o];
#pragma unroll
            for (int c = 0; c < CC; ++c) acc += aw1[o * CC + c] * pcol[c];
            h1[o] = fmaxf(acc, 0.0f);
        }
        float h2[16];
#pragma unroll
        for (int o = 0; o < 16; ++o) {
            float acc = ab2[o];
#pragma unroll
            for (int c = 0; c < 16; ++c) acc += aw2[o * 16 + c] * h1[c];
            h2[o] = fmaxf(acc, 0.0f);
        }
#pragma unroll
        for (int c = 0; c < CC; ++c) {
            float acc = abw[c];
#pragma unroll
            for (int k = 0; k < 16; ++k) acc += aww[c * 16 + k] * h2[k];
            afa[c] += pcol[c] * acc;
        }
    }

    // reduce afa across the 8 lanes sharing i, write nf = x + afa
#pragma unroll
    for (int c = 0; c < CC; ++c) {
        float v = afa[c];
        v += __shfl_xor(v, 1);
        v += __shfl_xor(v, 2);
        v += __shfl_xor(v, 4);
        if (jg == 0) nfs[c][i] = xi[c] + v;
    }
    __syncthreads();

    // ---- MLP layer 1: 35 -> 64
    {
        const int o = t & 63, ib = (t >> 6) << 3;
        float acc[8];
        float bb = b1[o];
#pragma unroll
        for (int k = 0; k < 8; ++k) acc[k] = bb;
        for (int c = 0; c < CC; ++c) {
            float w = w1T[c * 64 + o];
#pragma unroll
            for (int k = 0; k < 8; ++k) acc[k] += w * nfs[c][ib + k];
        }
#pragma unroll
        for (int k = 0; k < 8; ++k) h1s[o][ib + k] = fmaxf(acc[k], 0.0f);
    }
    __syncthreads();

    // ---- MLP layer 2: 64 -> 64
    {
        const int o = t & 63, ib = (t >> 6) << 3;
        float acc[8];
        float bb = b2[o];
#pragma unroll
        for (int k = 0; k < 8; ++k) acc[k] = bb;
        for (int c = 0; c < 64; ++c) {
            float w = w2T[c * 64 + o];
#pragma unroll
            for (int k = 0; k < 8; ++k) acc[k] += w * h1s[c][ib + k];
        }
#pragma unroll
        for (int k = 0; k < 8; ++k) h2s[o][ib + k] = fmaxf(acc[k], 0.0f);
    }
    __syncthreads();

    // ---- MLP layer 3: 64 -> 128, relu, maxpool over M
    {
        const int o = t & 127, ib = (t >> 7) << 4;
        float acc[16];
        float bb = b3[o];
#pragma unroll
        for (int k = 0; k < 16; ++k) acc[k] = bb;
        for (int c = 0; c < 64; ++c) {
            float w = w3T[c * 128 + o];
#pragma unroll
            for (int k = 0; k < 16; ++k) acc[k] += w * h2s[c][ib + k];
        }
        float mx = -1e30f;
#pragma unroll
        for (int k = 0; k < 16; ++k) mx = fmaxf(mx, fmaxf(acc[k], 0.0f));
        pmax[o][t >> 7] = mx;
    }
    __syncthreads();

    if (t < 128) {
        float v = fmaxf(pmax[t][0], pmax[t][1]);
        out[(b * 128 + t) * NP + p] = v;
    }
}

extern "C" void kernel_launch(void* const* d_in, const int* in_sizes, int n_in,
                              void* d_out, int out_size, void* d_ws, size_t ws_size,
                              hipStream_t stream)
{
    const float* xyz  = (const float*)d_in[0];
    const float* feat = (const float*)d_in[1];
    const float* aw1  = (const float*)d_in[2];
    const float* ab1  = (const float*)d_in[3];
    const float* aw2  = (const float*)d_in[4];
    const float* ab2  = (const float*)d_in[5];
    const float* aww  = (const float*)d_in[6];
    const float* abw  = (const float*)d_in[7];
    const float* mw1  = (const float*)d_in[8];
    const float* mb1  = (const float*)d_in[9];
    const float* mw2  = (const float*)d_in[10];
    const float* mb2  = (const float*)d_in[11];
    const float* mw3  = (const float*)d_in[12];
    const float* mb3  = (const float*)d_in[13];

    float* out    = (float*)d_out;
    float* newxyz = out;                  // (B, NP, 3) = 6144 floats
    float* out2   = out + BB * NP * 3;    // (B, 128, NP)

    int*   knn = (int*)d_ws;                                   // 2048*32 ints
    float* w1T = (float*)((char*)d_ws + (1 << 19));            // 35x64
    float* w2T = w1T + CC * 64;                                // 64x64
    float* w3T = w2T + 64 * 64;                                // 64x128

    fps_kernel<<<dim3(BB), dim3(256), 0, stream>>>(xyz, newxyz);
    prep_kernel<<<dim3(8), dim3(256), 0, stream>>>(mw1, mw2, mw3, w1T, w2T, w3T);
    knn_kernel<<<dim3(BB * NP), dim3(256), 0, stream>>>(xyz, newxyz, knn);
    afa_mlp_kernel<<<dim3(BB * NP), dim3(256), 0, stream>>>(
        xyz, feat, newxyz, knn,
        aw1, ab1, aw2, ab2, aww, abw,
        w1T, mb1, w2T, mb2, w3T, mb3, out2);
}

// Round 8
// 1298.277 us; speedup vs baseline: 1.1349x; 1.1349x over previous
//
#include <hip/hip_runtime.h>

#define BB 2
#define NN 4096
#define NP 1024
#define MM 32
#define CC 35
#define CIN 32

// key-only DPP max-combine (u64 key = dist_bits<<32 | ~idx)
#define KEY_DPP(CTRL) do { \
    int _lo = (int)(unsigned)key, _hi = (int)(unsigned)(key >> 32); \
    int _olo = __builtin_amdgcn_mov_dpp(_lo, CTRL, 0xF, 0xF, true); \
    int _ohi = __builtin_amdgcn_mov_dpp(_hi, CTRL, 0xF, 0xF, true); \
    unsigned long long _ok = ((unsigned long long)(unsigned)_ohi << 32) | (unsigned)_olo; \
    if (_ok > key) key = _ok; \
} while (0)

// ---------------- FPS: one block per batch, 4 waves ----------------
// R5 base (pc-table, nxs staging, key-only u64) with the two 64-lane
// shfl_xor hops replaced by: DPP xor1/2/4/8 (row-16 converged) -> 16
// u64 key-only LDS slots (stride 2 words: banks 0,2,..,30 -> conflict
// free; R7's 5-word slots aliased 4-way, 160 conflict-cy/step) ->
// barrier -> each lane reads slot (t&15) -> 4 DPP rounds converge.
__launch_bounds__(256)
__global__ void fps_kernel(const float* __restrict__ xyz, float* __restrict__ newxyz_out)
{
#pragma clang fp contract(off)
    const int b = blockIdx.x;
    const int t = threadIdx.x;
    const float* xb = xyz + b * NN * 3;

    __shared__ float4 pc[NN];                  // coord table for far-lookup
    __shared__ float nxs[NP * 3];              // newxyz staging
    __shared__ unsigned long long red[2][16];  // double-buffered row winners (key only)

    float px[16], py[16], pz[16], dist[16];
#pragma unroll
    for (int k = 0; k < 16; ++k) {
        int n = t + 256 * k;
        float x = xb[n * 3 + 0];
        float y = xb[n * 3 + 1];
        float z = xb[n * 3 + 2];
        px[k] = x; py[k] = y; pz[k] = z;
        dist[k] = 1e10f;
        pc[n] = make_float4(x, y, z, 0.0f);
    }
    __syncthreads();

    int far = 0;
    for (int s = 0; s < NP; ++s) {
        float4 c = pc[far];                    // uniform LDS broadcast
        if (t == 0) {
            nxs[s * 3 + 0] = c.x;
            nxs[s * 3 + 1] = c.y;
            nxs[s * 3 + 2] = c.z;
        }
        const float cx = c.x, cy = c.y, cz = c.z;

        // update dists, local argmax (ascending k + strict > == first-index ties)
        float bv = -1.0f; int bi = 0;
#pragma unroll
        for (int k = 0; k < 16; ++k) {
            float dx = px[k] - cx, dy = py[k] - cy, dz = pz[k] - cz;
            float d = (dx * dx + dy * dy) + dz * dz;
            float dd = fminf(dist[k], d);
            dist[k] = dd;
            if (dd > bv) { bv = dd; bi = t + 256 * k; }
        }

        // pack: max key == max dist; low word ~idx -> smallest index on ties
        unsigned long long key =
            ((unsigned long long)(unsigned)__float_as_int(bv) << 32)
            | (unsigned)(0xFFFFFFFFu - (unsigned)bi);

        KEY_DPP(0xB1);   // xor 1
        KEY_DPP(0x4E);   // xor 2
        KEY_DPP(0x141);  // cross-quad combine (quads converged)
        KEY_DPP(0x140);  // cross-octet combine -> row of 16 converged

        const int buf = s & 1;
        if ((t & 15) == 0) red[buf][t >> 4] = key;   // 16 row winners
        __syncthreads();

        key = red[buf][t & 15];     // conflict-free b64: banks 0,2,..,30
        KEY_DPP(0xB1);
        KEY_DPP(0x4E);
        KEY_DPP(0x141);
        KEY_DPP(0x140);
        far = (int)(0xFFFFFFFFu - (unsigned)key);    // uniform across block
    }

    __syncthreads();
#pragma unroll
    for (int j = 0; j < 12; ++j) {
        int i = t + 256 * j;
        newxyz_out[b * NP * 3 + i] = nxs[i];
    }
}

// ---------------- prep: transpose MLP weights (coalesced o-reads later) ----
__global__ void prep_kernel(const float* __restrict__ w1, const float* __restrict__ w2,
                            const float* __restrict__ w3,
                            float* __restrict__ w1T, float* __restrict__ w2T,
                            float* __restrict__ w3T)
{
    int t = blockIdx.x * 256 + threadIdx.x;
    int stride = gridDim.x * 256;
    for (int i = t; i < 64 * CC; i += stride) { int o = i / CC, c = i % CC; w1T[c * 64 + o] = w1[i]; }
    for (int i = t; i < 64 * 64; i += stride) { int o = i >> 6, c = i & 63; w2T[c * 64 + o] = w2[i]; }
    for (int i = t; i < 128 * 64; i += stride) { int o = i >> 6, c = i & 63; w3T[c * 128 + o] = w3[i]; }
}

// ---------------- mega: kNN + gather + AFA + MLP + maxpool, one block/(b,p) ----
__launch_bounds__(256)
__global__ void mega_kernel(const float* __restrict__ xyz, const float* __restrict__ feat,
                            const float* __restrict__ newxyz,
                            const float* __restrict__ aw1, const float* __restrict__ ab1,
                            const float* __restrict__ aw2, const float* __restrict__ ab2,
                            const float* __restrict__ aww, const float* __restrict__ abw,
                            const float* __restrict__ w1T, const float* __restrict__ b1,
                            const float* __restrict__ w2T, const float* __restrict__ b2,
                            const float* __restrict__ w3T, const float* __restrict__ b3,
                            float* __restrict__ out)
{
    const int bp = blockIdx.x;
    const int b = bp >> 10, p = bp & 1023;
    const int t = threadIdx.x;

    __shared__ float dist[NN];
    __shared__ float redV[4];
    __shared__ int   redI[4];
    __shared__ int   idxs[MM];
    __shared__ float xs[CC][MM];
    __shared__ float nfs[CC][MM];
    __shared__ float h1s[64][36];    // pad 36: 16B-aligned float4 rows
    __shared__ float h2s[64][36];
    __shared__ float pmax[128][2];

    // ---- kNN phase (exact arithmetic: contract off) ----
    {
#pragma clang fp contract(off)
        const float* xb = xyz + b * NN * 3;
        const float qx = newxyz[bp * 3 + 0];
        const float qy = newxyz[bp * 3 + 1];
        const float qz = newxyz[bp * 3 + 2];
        const float qn = (qx * qx + qy * qy) + qz * qz;

#pragma unroll
        for (int k = 0; k < 16; ++k) {
            int n = t + 256 * k;
            float x = xb[n * 3 + 0], y = xb[n * 3 + 1], z = xb[n * 3 + 2];
            float xn = (x * x + y * y) + z * z;
            float dt = (qx * x + qy * y) + qz * z;
            dist[n] = (qn + xn) - 2.0f * dt;
        }
        __syncthreads();

        for (int r = 0; r < MM; ++r) {
            float bv = 1e30f; int bi = NN;
#pragma unroll
            for (int k = 0; k < 16; ++k) {
                int n = t + 256 * k;
                float v = dist[n];
                if (v < bv) { bv = v; bi = n; }
            }
#pragma unroll
            for (int off = 1; off < 64; off <<= 1) {
                float ov = __shfl_xor(bv, off);
                int   oi = __shfl_xor(bi, off);
                if (ov < bv || (ov == bv && oi < bi)) { bv = ov; bi = oi; }
            }
            if ((t & 63) == 0) { redV[t >> 6] = bv; redI[t >> 6] = bi; }
            __syncthreads();
            bv = redV[0]; bi = redI[0];
#pragma unroll
            for (int w = 1; w < 4; ++w) {
                float ov = redV[w]; int oi = redI[w];
                if (ov < bv || (ov == bv && oi < bi)) { bv = ov; bi = oi; }
            }
            if (t == 0) { idxs[r] = bi; dist[bi] = 1e30f; }
            __syncthreads();
        }
    }

    // ---- gather x = concat(gxyz, gfeat) as [C][M] ----
    {
        const int m = t & 31, c0 = t >> 5;
        const int id = idxs[m] & (NN - 1);   // defensive mask (no-op for valid idx)
        for (int c = c0; c < CC; c += 8) {
            float v;
            if (c < 3) v = xyz[(b * NN + id) * 3 + c] - newxyz[bp * 3 + c];
            else       v = feat[(b * CIN + (c - 3)) * NN + id];
            xs[c][m] = v;
        }
    }
    __syncthreads();

    // ---- AFA: thread (i = t>>3, jg = t&7) handles j in {jg, jg+8, jg+16, jg+24}
    const int i = t >> 3, jg = t & 7;
    float xi[CC], afa[CC];
#pragma unroll
    for (int c = 0; c < CC; ++c) { xi[c] = xs[c][i]; afa[c] = 0.0f; }

#pragma unroll
    for (int jk = 0; jk < 4; ++jk) {
        const int j = jg + 8 * jk;
        float pcol[CC];
#pragma unroll
        for (int c = 0; c < CC; ++c) {
            float v = xi[c] - xs[c][j];
            if (i == j) v = xi[c];       // xi - xj + xi*eye
            pcol[c] = v;
        }
        float h1[16];
#pragma unroll
        for (int o = 0; o < 16; ++o) {
            float acc = ab1[o];
#pragma unroll
            for (int c = 0; c < CC; ++c) acc += aw1[o * CC + c] * pcol[c];
            h1[o] = fmaxf(acc, 0.0f);
        }
        float h2[16];
#pragma unroll
        for (int o = 0; o < 16; ++o) {
            float acc = ab2[o];
#pragma unroll
            for (int c = 0; c < 16; ++c) acc += aw2[o * 16 + c] * h1[c];
            h2[o] = fmaxf(acc, 0.0f);
        }
#pragma unroll
        for (int c = 0; c < CC; ++c) {
            float acc = abw[c];
#pragma unroll
            for (int k = 0; k < 16; ++k) acc += aww[c * 16 + k] * h2[k];
            afa[c] += pcol[c] * acc;
        }
    }

    // reduce afa across the 8 lanes sharing i, write nf = x + afa
#pragma unroll
    for (int c = 0; c < CC; ++c) {
        float v = afa[c];
        v += __shfl_xor(v, 1);
        v += __shfl_xor(v, 2);
        v += __shfl_xor(v, 4);
        if (jg == 0) nfs[c][i] = xi[c] + v;
    }
    __syncthreads();

    // ---- MLP layer 1: 35 -> 64 (broadcast float4 reads from nfs)
    {
        const int o = t & 63, ib = (t >> 6) << 3;
        float acc[8];
        float bb = b1[o];
#pragma unroll
        for (int k = 0; k < 8; ++k) acc[k] = bb;
        for (int c = 0; c < CC; ++c) {
            float w = w1T[c * 64 + o];
            const float4* np4 = (const float4*)&nfs[c][ib];   // (c*32+ib)*4 % 16 == 0
            float4 n0 = np4[0], n1 = np4[1];
            acc[0] += w * n0.x; acc[1] += w * n0.y; acc[2] += w * n0.z; acc[3] += w * n0.w;
            acc[4] += w * n1.x; acc[5] += w * n1.y; acc[6] += w * n1.z; acc[7] += w * n1.w;
        }
        float4 r0 = { fmaxf(acc[0], 0.0f), fmaxf(acc[1], 0.0f), fmaxf(acc[2], 0.0f), fmaxf(acc[3], 0.0f) };
        float4 r1 = { fmaxf(acc[4], 0.0f), fmaxf(acc[5], 0.0f), fmaxf(acc[6], 0.0f), fmaxf(acc[7], 0.0f) };
        *(float4*)&h1s[o][ib]     = r0;    // (o*36+ib)*4 % 16 == 0
        *(float4*)&h1s[o][ib + 4] = r1;
    }
    __syncthreads();

    // ---- MLP layer 2: 64 -> 64
    {
        const int o = t & 63, ib = (t >> 6) << 3;
        float acc[8];
        float bb = b2[o];
#pragma unroll
        for (int k = 0; k < 8; ++k) acc[k] = bb;
        for (int c = 0; c < 64; ++c) {
            float w = w2T[c * 64 + o];
            const float4* hp4 = (const float4*)&h1s[c][ib];
            float4 h0 = hp4[0], h1v = hp4[1];
            acc[0] += w * h0.x; acc[1] += w * h0.y; acc[2] += w * h0.z; acc[3] += w * h0.w;
            acc[4] += w * h1v.x; acc[5] += w * h1v.y; acc[6] += w * h1v.z; acc[7] += w * h1v.w;
        }
        float4 r0 = { fmaxf(acc[0], 0.0f), fmaxf(acc[1], 0.0f), fmaxf(acc[2], 0.0f), fmaxf(acc[3], 0.0f) };
        float4 r1 = { fmaxf(acc[4], 0.0f), fmaxf(acc[5], 0.0f), fmaxf(acc[6], 0.0f), fmaxf(acc[7], 0.0f) };
        *(float4*)&h2s[o][ib]     = r0;
        *(float4*)&h2s[o][ib + 4] = r1;
    }
    __syncthreads();

    // ---- MLP layer 3: 64 -> 128, relu, maxpool over M
    {
        const int o = t & 127, ib = (t >> 7) << 4;
        float acc[16];
        float bb = b3[o];
#pragma unroll
        for (int k = 0; k < 16; ++k) acc[k] = bb;
        for (int c = 0; c < 64; ++c) {
            float w = w3T[c * 128 + o];
            const float4* hp4 = (const float4*)&h2s[c][ib];
            float4 h0 = hp4[0], h1v = hp4[1], h2v = hp4[2], h3v = hp4[3];
            acc[0]  += w * h0.x;  acc[1]  += w * h0.y;  acc[2]  += w * h0.z;  acc[3]  += w * h0.w;
            acc[4]  += w * h1v.x; acc[5]  += w * h1v.y; acc[6]  += w * h1v.z; acc[7]  += w * h1v.w;
            acc[8]  += w * h2v.x; acc[9]  += w * h2v.y; acc[10] += w * h2v.z; acc[11] += w * h2v.w;
            acc[12] += w * h3v.x; acc[13] += w * h3v.y; acc[14] += w * h3v.z; acc[15] += w * h3v.w;
        }
        float mx = -1e30f;
#pragma unroll
        for (int k = 0; k < 16; ++k) mx = fmaxf(mx, fmaxf(acc[k], 0.0f));
        pmax[o][t >> 7] = mx;
    }
    __syncthreads();

    if (t < 128) {
        float v = fmaxf(pmax[t][0], pmax[t][1]);
        out[(b * 128 + t) * NP + p] = v;
    }
}

extern "C" void kernel_launch(void* const* d_in, const int* in_sizes, int n_in,
                              void* d_out, int out_size, void* d_ws, size_t ws_size,
                              hipStream_t stream)
{
    const float* xyz  = (const float*)d_in[0];
    const float* feat = (const float*)d_in[1];
    const float* aw1  = (const float*)d_in[2];
    const float* ab1  = (const float*)d_in[3];
    const float* aw2  = (const float*)d_in[4];
    const float* ab2  = (const float*)d_in[5];
    const float* aww  = (const float*)d_in[6];
    const float* abw  = (const float*)d_in[7];
    const float* mw1  = (const float*)d_in[8];
    const float* mb1  = (const float*)d_in[9];
    const float* mw2  = (const float*)d_in[10];
    const float* mb2  = (const float*)d_in[11];
    const float* mw3  = (const float*)d_in[12];
    const float* mb3  = (const float*)d_in[13];

    float* out    = (float*)d_out;
    float* newxyz = out;                  // (B, NP, 3) = 6144 floats
    float* out2   = out + BB * NP * 3;    // (B, 128, NP)

    float* w1T = (float*)d_ws;            // 35x64
    float* w2T = w1T + CC * 64;           // 64x64
    float* w3T = w2T + 64 * 64;           // 64x128

    fps_kernel<<<dim3(BB), dim3(256), 0, stream>>>(xyz, newxyz);
    prep_kernel<<<dim3(8), dim3(256), 0, stream>>>(mw1, mw2, mw3, w1T, w2T, w3T);
    mega_kernel<<<dim3(BB * NP), dim3(256), 0, stream>>>(
        xyz, feat, newxyz,
        aw1, ab1, aw2, ab2, aww, abw,
        w1T, mb1, w2T, mb2, w3T, mb3, out2);
}

// Round 9
// 813.203 us; speedup vs baseline: 1.8118x; 1.5965x over previous
//
#include <hip/hip_runtime.h>

#define BB 2
#define NN 4096
#define NP 1024
#define MM 32
#define CC 35
#define CIN 32

// key-only DPP max-combine (u64 key = dist_bits<<32 | ~idx)
#define KEY_DPP(CTRL) do { \
    int _lo = (int)(unsigned)key, _hi = (int)(unsigned)(key >> 32); \
    int _olo = __builtin_amdgcn_mov_dpp(_lo, CTRL, 0xF, 0xF, true); \
    int _ohi = __builtin_amdgcn_mov_dpp(_hi, CTRL, 0xF, 0xF, true); \
    unsigned long long _ok = ((unsigned long long)(unsigned)_ohi << 32) | (unsigned)_olo; \
    if (_ok > key) key = _ok; \
} while (0)

// ---------------- FPS (blocks 0..BB-1) + weight-transpose prep (blocks BB..BB+7) ----
// fps: R8 structure (best measured): pc-table, nxs staging, key-only u64,
// DPP xor1/2/4/8 -> 16 conflict-free u64 slots -> barrier -> slot(t&15)
// -> 4 DPP rounds. prep blocks run concurrently on other CUs (free).
__launch_bounds__(256)
__global__ void fps_prep_kernel(const float* __restrict__ xyz, float* __restrict__ newxyz_out,
                                const float* __restrict__ w1, const float* __restrict__ w2,
                                const float* __restrict__ w3,
                                float* __restrict__ w1T, float* __restrict__ w2T,
                                float* __restrict__ w3T)
{
#pragma clang fp contract(off)
    const int t = threadIdx.x;

    if (blockIdx.x >= BB) {   // ---- prep: transpose MLP weights ----
        int g = (blockIdx.x - BB) * 256 + t;
        int stride = 8 * 256;
        for (int i = g; i < 64 * CC; i += stride) { int o = i / CC, c = i % CC; w1T[c * 64 + o] = w1[i]; }
        for (int i = g; i < 64 * 64; i += stride) { int o = i >> 6, c = i & 63; w2T[c * 64 + o] = w2[i]; }
        for (int i = g; i < 128 * 64; i += stride) { int o = i >> 6, c = i & 63; w3T[c * 128 + o] = w3[i]; }
        return;
    }

    const int b = blockIdx.x;
    const float* xb = xyz + b * NN * 3;

    __shared__ float4 pc[NN];                  // coord table for far-lookup
    __shared__ float nxs[NP * 3];              // newxyz staging
    __shared__ unsigned long long red[2][16];  // double-buffered row winners

    float px[16], py[16], pz[16], dist[16];
#pragma unroll
    for (int k = 0; k < 16; ++k) {
        int n = t + 256 * k;
        float x = xb[n * 3 + 0];
        float y = xb[n * 3 + 1];
        float z = xb[n * 3 + 2];
        px[k] = x; py[k] = y; pz[k] = z;
        dist[k] = 1e10f;
        pc[n] = make_float4(x, y, z, 0.0f);
    }
    __syncthreads();

    int far = 0;
    for (int s = 0; s < NP; ++s) {
        float4 c = pc[far];                    // uniform LDS broadcast
        if (t == 0) {
            nxs[s * 3 + 0] = c.x;
            nxs[s * 3 + 1] = c.y;
            nxs[s * 3 + 2] = c.z;
        }
        const float cx = c.x, cy = c.y, cz = c.z;

        float bv = -1.0f; int bi = 0;
#pragma unroll
        for (int k = 0; k < 16; ++k) {
            float dx = px[k] - cx, dy = py[k] - cy, dz = pz[k] - cz;
            float d = (dx * dx + dy * dy) + dz * dz;
            float dd = fminf(dist[k], d);
            dist[k] = dd;
            if (dd > bv) { bv = dd; bi = t + 256 * k; }
        }

        unsigned long long key =
            ((unsigned long long)(unsigned)__float_as_int(bv) << 32)
            | (unsigned)(0xFFFFFFFFu - (unsigned)bi);

        KEY_DPP(0xB1);   // xor 1
        KEY_DPP(0x4E);   // xor 2
        KEY_DPP(0x141);  // cross-quad combine
        KEY_DPP(0x140);  // cross-octet -> row of 16 converged

        const int buf = s & 1;
        if ((t & 15) == 0) red[buf][t >> 4] = key;
        __syncthreads();

        key = red[buf][t & 15];
        KEY_DPP(0xB1);
        KEY_DPP(0x4E);
        KEY_DPP(0x141);
        KEY_DPP(0x140);
        far = (int)(0xFFFFFFFFu - (unsigned)key);
    }

    __syncthreads();
#pragma unroll
    for (int j = 0; j < 12; ++j) {
        int i = t + 256 * j;
        newxyz_out[b * NP * 3 + i] = nxs[i];
    }
}

// ---------------- kNN: one block per (b,p) (R6 structure: small LDS) ----
__launch_bounds__(256)
__global__ void knn_kernel(const float* __restrict__ xyz, const float* __restrict__ newxyz,
                           int* __restrict__ knn_out)
{
#pragma clang fp contract(off)
    const int bp = blockIdx.x;
    const int b = bp >> 10;
    const int t = threadIdx.x;
    const float* xb = xyz + b * NN * 3;

    const float qx = newxyz[bp * 3 + 0];
    const float qy = newxyz[bp * 3 + 1];
    const float qz = newxyz[bp * 3 + 2];
    const float qn = (qx * qx + qy * qy) + qz * qz;

    __shared__ float dist[NN];
    __shared__ float redV[4];
    __shared__ int   redI[4];

#pragma unroll
    for (int k = 0; k < 16; ++k) {
        int n = t + 256 * k;
        float x = xb[n * 3 + 0], y = xb[n * 3 + 1], z = xb[n * 3 + 2];
        float xn = (x * x + y * y) + z * z;
        float dt = (qx * x + qy * y) + qz * z;
        dist[n] = (qn + xn) - 2.0f * dt;
    }
    __syncthreads();

    for (int r = 0; r < MM; ++r) {
        float bv = 1e30f; int bi = NN;
#pragma unroll
        for (int k = 0; k < 16; ++k) {
            int n = t + 256 * k;
            float v = dist[n];
            if (v < bv) { bv = v; bi = n; }
        }
#pragma unroll
        for (int off = 1; off < 64; off <<= 1) {
            float ov = __shfl_xor(bv, off);
            int   oi = __shfl_xor(bi, off);
            if (ov < bv || (ov == bv && oi < bi)) { bv = ov; bi = oi; }
        }
        if ((t & 63) == 0) { redV[t >> 6] = bv; redI[t >> 6] = bi; }
        __syncthreads();
        bv = redV[0]; bi = redI[0];
#pragma unroll
        for (int w = 1; w < 4; ++w) {
            float ov = redV[w]; int oi = redI[w];
            if (ov < bv || (ov == bv && oi < bi)) { bv = ov; bi = oi; }
        }
        if (t == 0) { knn_out[bp * MM + r] = bi; dist[bi] = 1e30f; }
        __syncthreads();
    }
}

// ---------------- gather + AFA (u-factorized) + MLP + maxpool ----------------
// AFA layer-1 factorization: W1@pair[:,i,j] = u_i - u_j (+ u_i if i==j),
// u = W1@x computed once per block (per-pair cost 1541 -> ~940 FMA).
// Diag is exact: u_i - u_i + u_i == u_i. Reassoc delta ~1e-5 << threshold.
__launch_bounds__(256)
__global__ void afa_mlp_kernel(const float* __restrict__ xyz, const float* __restrict__ feat,
                               const float* __restrict__ newxyz, const int* __restrict__ knn,
                               const float* __restrict__ aw1, const float* __restrict__ ab1,
                               const float* __restrict__ aw2, const float* __restrict__ ab2,
                               const float* __restrict__ aww, const float* __restrict__ abw,
                               const float* __restrict__ w1T, const float* __restrict__ b1,
                               const float* __restrict__ w2T, const float* __restrict__ b2,
                               const float* __restrict__ w3T, const float* __restrict__ b3,
                               float* __restrict__ out)
{
    const int bp = blockIdx.x;
    const int b = bp >> 10, p = bp & 1023;
    const int t = threadIdx.x;

    __shared__ int   idxs[MM];
    __shared__ float xs_t[MM][36];   // [m][c], pad 36 -> conflict-free b128 rows
    __shared__ float u_lds[MM][20];  // [m][o], pad 20 -> conflict-free b128 rows
    __shared__ float nfs[CC][MM];
    __shared__ float h1s[64][36];    // pad 36: 16B-aligned float4 rows
    __shared__ float h2s[64][36];
    __shared__ float pmax[128][2];

    if (t < MM) idxs[t] = knn[bp * MM + t];
    __syncthreads();

    {   // gather x = concat(gxyz, gfeat) as [m][c]
        const int m = t & 31, c0 = t >> 5;
        const int id = idxs[m] & (NN - 1);
        for (int c = c0; c < CC; c += 8) {
            float v;
            if (c < 3) v = xyz[(b * NN + id) * 3 + c] - newxyz[bp * 3 + c];
            else       v = feat[(b * CIN + (c - 3)) * NN + id];
            xs_t[m][c] = v;
        }
        if (c0 == 0) xs_t[m][35] = 0.0f;   // pad word (read by b128, never used)
    }
    __syncthreads();

    const int i = t >> 3, jg = t & 7;

    // xi = own row (9 x b128, broadcast within 8-lane groups)
    float xi[36];
    {
        const float4* xp = (const float4*)&xs_t[i][0];
#pragma unroll
        for (int q = 0; q < 9; ++q) {
            float4 v = xp[q];
            xi[4 * q] = v.x; xi[4 * q + 1] = v.y; xi[4 * q + 2] = v.z; xi[4 * q + 3] = v.w;
        }
    }

    // ---- phase A: u_i = W1 @ x_i (redundant x8 across jg; weights via s_load)
    float u16[16];
#pragma unroll
    for (int o = 0; o < 16; ++o) {
        float acc = 0.0f;
#pragma unroll
        for (int c = 0; c < CC; ++c) acc += aw1[o * CC + c] * xi[c];
        u16[o] = acc;
    }
    if (jg == 0) {
        float4* up = (float4*)&u_lds[i][0];
#pragma unroll
        for (int q = 0; q < 4; ++q)
            up[q] = make_float4(u16[4 * q], u16[4 * q + 1], u16[4 * q + 2], u16[4 * q + 3]);
    }
    __syncthreads();

    // ---- phase B: per pair (i, j = jg+8*jk)
    float afa[CC];
#pragma unroll
    for (int c = 0; c < CC; ++c) afa[c] = 0.0f;

#pragma unroll
    for (int jk = 0; jk < 4; ++jk) {
        const int j = jg + 8 * jk;
        const bool diag = (i == j);

        float uj[16];
        {
            const float4* up = (const float4*)&u_lds[j][0];
#pragma unroll
            for (int q = 0; q < 4; ++q) {
                float4 v = up[q];
                uj[4 * q] = v.x; uj[4 * q + 1] = v.y; uj[4 * q + 2] = v.z; uj[4 * q + 3] = v.w;
            }
        }

        float h1[16];
#pragma unroll
        for (int o = 0; o < 16; ++o) {
            float s = u16[o] - uj[o];
            if (diag) s += u16[o];
            h1[o] = fmaxf(s + ab1[o], 0.0f);
        }

        float xj[36];
        {
            const float4* xp = (const float4*)&xs_t[j][0];
#pragma unroll
            for (int q = 0; q < 9; ++q) {
                float4 v = xp[q];
                xj[4 * q] = v.x; xj[4 * q + 1] = v.y; xj[4 * q + 2] = v.z; xj[4 * q + 3] = v.w;
            }
        }

        float h2[16];
#pragma unroll
        for (int o = 0; o < 16; ++o) {
            float acc = ab2[o];
#pragma unroll
            for (int c = 0; c < 16; ++c) acc += aw2[o * 16 + c] * h1[c];
            h2[o] = fmaxf(acc, 0.0f);
        }

#pragma unroll
        for (int c = 0; c < CC; ++c) {
            float acc = abw[c];
#pragma unroll
            for (int k = 0; k < 16; ++k) acc += aww[c * 16 + k] * h2[k];
            float pc_ = xi[c] - xj[c];
            if (diag) pc_ += xi[c];
            afa[c] += pc_ * acc;
        }
    }

    // reduce afa across the 8 lanes sharing i, write nf = x + afa as [c][m]
#pragma unroll
    for (int c = 0; c < CC; ++c) {
        float v = afa[c];
        v += __shfl_xor(v, 1);
        v += __shfl_xor(v, 2);
        v += __shfl_xor(v, 4);
        if (jg == 0) nfs[c][i] = xi[c] + v;
    }
    __syncthreads();

    // ---- MLP layer 1: 35 -> 64
    {
        const int o = t & 63, ib = (t >> 6) << 3;
        float acc[8];
        float bb = b1[o];
#pragma unroll
        for (int k = 0; k < 8; ++k) acc[k] = bb;
        for (int c = 0; c < CC; ++c) {
            float w = w1T[c * 64 + o];
            const float4* np4 = (const float4*)&nfs[c][ib];
            float4 n0 = np4[0], n1 = np4[1];
            acc[0] += w * n0.x; acc[1] += w * n0.y; acc[2] += w * n0.z; acc[3] += w * n0.w;
            acc[4] += w * n1.x; acc[5] += w * n1.y; acc[6] += w * n1.z; acc[7] += w * n1.w;
        }
        float4 r0 = { fmaxf(acc[0], 0.0f), fmaxf(acc[1], 0.0f), fmaxf(acc[2], 0.0f), fmaxf(acc[3], 0.0f) };
        float4 r1 = { fmaxf(acc[4], 0.0f), fmaxf(acc[5], 0.0f), fmaxf(acc[6], 0.0f), fmaxf(acc[7], 0.0f) };
        *(float4*)&h1s[o][ib]     = r0;
        *(float4*)&h1s[o][ib + 4] = r1;
    }
    __syncthreads();

    // ---- MLP layer 2: 64 -> 64
    {
        const int o = t & 63, ib = (t >> 6) << 3;
        float acc[8];
        float bb = b2[o];
#pragma unroll
        for (int k = 0; k < 8; ++k) acc[k] = bb;
        for (int c = 0; c < 64; ++c) {
            float w = w2T[c * 64 + o];
            const float4* hp4 = (const float4*)&h1s[c][ib];
            float4 h0 = hp4[0], h1v = hp4[1];
            acc[0] += w * h0.x; acc[1] += w * h0.y; acc[2] += w * h0.z; acc[3] += w * h0.w;
            acc[4] += w * h1v.x; acc[5] += w * h1v.y; acc[6] += w * h1v.z; acc[7] += w * h1v.w;
        }
        float4 r0 = { fmaxf(acc[0], 0.0f), fmaxf(acc[1], 0.0f), fmaxf(acc[2], 0.0f), fmaxf(acc[3], 0.0f) };
        float4 r1 = { fmaxf(acc[4], 0.0f), fmaxf(acc[5], 0.0f), fmaxf(acc[6], 0.0f), fmaxf(acc[7], 0.0f) };
        *(float4*)&h2s[o][ib]     = r0;
        *(float4*)&h2s[o][ib + 4] = r1;
    }
    __syncthreads();

    // ---- MLP layer 3: 64 -> 128, relu, maxpool over M
    {
        const int o = t & 127, ib = (t >> 7) << 4;
        float acc[16];
        float bb = b3[o];
#pragma unroll
        for (int k = 0; k < 16; ++k) acc[k] = bb;
        for (int c = 0; c < 64; ++c) {
            float w = w3T[c * 128 + o];
            const float4* hp4 = (const float4*)&h2s[c][ib];
            float4 h0 = hp4[0], h1v = hp4[1], h2v = hp4[2], h3v = hp4[3];
            acc[0]  += w * h0.x;  acc[1]  += w * h0.y;  acc[2]  += w * h0.z;  acc[3]  += w * h0.w;
            acc[4]  += w * h1v.x; acc[5]  += w * h1v.y; acc[6]  += w * h1v.z; acc[7]  += w * h1v.w;
            acc[8]  += w * h2v.x; acc[9]  += w * h2v.y; acc[10] += w * h2v.z; acc[11] += w * h2v.w;
            acc[12] += w * h3v.x; acc[13] += w * h3v.y; acc[14] += w * h3v.z; acc[15] += w * h3v.w;
        }
        float mx = -1e30f;
#pragma unroll
        for (int k = 0; k < 16; ++k) mx = fmaxf(mx, fmaxf(acc[k], 0.0f));
        pmax[o][t >> 7] = mx;
    }
    __syncthreads();

    if (t < 128) {
        float v = fmaxf(pmax[t][0], pmax[t][1]);
        out[(b * 128 + t) * NP + p] = v;
    }
}

extern "C" void kernel_launch(void* const* d_in, const int* in_sizes, int n_in,
                              void* d_out, int out_size, void* d_ws, size_t ws_size,
                              hipStream_t stream)
{
    const float* xyz  = (const float*)d_in[0];
    const float* feat = (const float*)d_in[1];
    const float* aw1  = (const float*)d_in[2];
    const float* ab1  = (const float*)d_in[3];
    const float* aw2  = (const float*)d_in[4];
    const float* ab2  = (const float*)d_in[5];
    const float* aww  = (const float*)d_in[6];
    const float* abw  = (const float*)d_in[7];
    const float* mw1  = (const float*)d_in[8];
    const float* mb1  = (const float*)d_in[9];
    const float* mw2  = (const float*)d_in[10];
    const float* mb2  = (const float*)d_in[11];
    const float* mw3  = (const float*)d_in[12];
    const float* mb3  = (const float*)d_in[13];

    float* out    = (float*)d_out;
    float* newxyz = out;                  // (B, NP, 3) = 6144 floats
    float* out2   = out + BB * NP * 3;    // (B, 128, NP)

    int*   knn = (int*)d_ws;                                   // 2048*32 ints
    float* w1T = (float*)((char*)d_ws + (1 << 19));            // 35x64
    float* w2T = w1T + CC * 64;                                // 64x64
    float* w3T = w2T + 64 * 64;                                // 64x128

    fps_prep_kernel<<<dim3(BB + 8), dim3(256), 0, stream>>>(xyz, newxyz,
                                                            mw1, mw2, mw3, w1T, w2T, w3T);
    knn_kernel<<<dim3(BB * NP), dim3(256), 0, stream>>>(xyz, newxyz, knn);
    afa_mlp_kernel<<<dim3(BB * NP), dim3(256), 0, stream>>>(
        xyz, feat, newxyz, knn,
        aw1, ab1, aw2, ab2, aww, abw,
        w1T, mb1, w2T, mb2, w3T, mb3, out2);
}